// Round 6
// baseline (227.658 us; speedup 1.0000x reference)
//
#include <hip/hip_runtime.h>
#include <hip/hip_bf16.h>

#define NUM_D1 270
#define NUM_B  128
#define NUM_C  273
#define NUM_T  1024
#define KL     1024      // K*K = 32*32
#define TW     320       // trig table padded width
#define CP     288       // padded C for a[] (9 * 32)
#define CW     296       // wg / X-LDS row stride in elems (592 B = 148 dw == 20 mod 32)
#define ROWB   (CW * 2)  // 592 bytes

#define XB_BYTES (64 * ROWB)              // 37,888
#define LDS4_TOTAL (2 * XB_BYTES)         // 75,776

typedef float f32x4 __attribute__((ext_vector_type(4)));
typedef __bf16 bf16x8 __attribute__((ext_vector_type(8)));

static __device__ __forceinline__ unsigned short f2bf(float f) {
  unsigned u = __float_as_uint(f);
  unsigned r = (u + 0x7fffu + ((u >> 16) & 1u)) >> 16;   // RNE
  return (unsigned short)r;
}

// Kernel 0: trig tables cos/sin(2*pi*(k*x + l*y)) for all (kl, c)
__global__ __launch_bounds__(256) void k_trig(const float* __restrict__ loc,
                                              float* __restrict__ cosT,
                                              float* __restrict__ sinT) {
  int idx = blockIdx.x * 256 + threadIdx.x;   // 0 .. 1024*320-1
  int kl = idx / TW;
  int c  = idx - kl * TW;
  float cv = 0.f, sv = 0.f;
  if (c < NUM_C) {
    float x = loc[2 * c], y = loc[2 * c + 1];
    float kf = (float)(kl >> 5), lf = (float)(kl & 31);
    float ph = 6.283185307179586f * (kf * x + lf * y);
    sincosf(ph, &sv, &cv);
  }
  cosT[idx] = cv;
  sinT[idx] = sv;
}

// Kernel 1: a[j,c] = sum_kl z_re[j,kl]*cos[kl,c] + z_im[j,kl]*sin[kl,c]
__global__ __launch_bounds__(1024) void k_agemm(const float* __restrict__ z_re,
                                                const float* __restrict__ z_im,
                                                const float* __restrict__ cosT,
                                                const float* __restrict__ sinT,
                                                float* __restrict__ a) {
  __shared__ float sm[4][8][64];
  int tid = threadIdx.x;
  int lane = tid & 63;
  int g = tid >> 6;            // 0..15
  int p = g >> 3;              // 0..1
  int q = g & 7;               // 0..7
  int jb = blockIdx.x;         // 0..67
  int cb = blockIdx.y;         // 0..4
  int c = cb * 64 + lane;      // < 320, in-bounds of padded table
  int j_a = jb * 4 + p;        // <= 269
  int j_b = j_a + 2;           // <= 271
  int jeb = (j_b < NUM_D1) ? j_b : 0;
  const float* zr0 = z_re + (size_t)j_a * KL;
  const float* zi0 = z_im + (size_t)j_a * KL;
  const float* zr1 = z_re + (size_t)jeb * KL;
  const float* zi1 = z_im + (size_t)jeb * KL;
  float a0 = 0.f, a1 = 0.f;
  int k0 = q * 128;
  #pragma unroll 4
  for (int kk = k0; kk < k0 + 128; ++kk) {
    float cv = cosT[kk * TW + c];
    float sv = sinT[kk * TW + c];
    a0 = fmaf(zr0[kk], cv, a0);
    a0 = fmaf(zi0[kk], sv, a0);
    a1 = fmaf(zr1[kk], cv, a1);
    a1 = fmaf(zi1[kk], sv, a1);
  }
  sm[p][q][lane] = a0;
  sm[p + 2][q][lane] = a1;
  __syncthreads();
  if (tid < 256) {
    int jl = tid >> 6;          // 0..3
    int l2 = tid & 63;
    int j = jb * 4 + jl;
    int c2 = cb * 64 + l2;
    float s = 0.f;
    #pragma unroll
    for (int qq = 0; qq < 8; ++qq) s += sm[jl][qq][l2];
    if (j < NUM_D1 && c2 < NUM_C) a[j * CP + c2] = s;
  }
}

// Kernel 2: w[j,:] = softmax_c(a[j,:]) -> bf16 into wg[288 rows][CW=296 stride], zero-padded
__global__ __launch_bounds__(256) void k_softmax(const float* __restrict__ a,
                                                 unsigned short* __restrict__ wg) {
  int wv = threadIdx.x >> 6;
  int lane = threadIdx.x & 63;
  int j = blockIdx.x * 4 + wv;   // < 288 (grid 72)
  if (j >= NUM_D1) {
    for (int c = lane; c < CW; c += 64) wg[j * CW + c] = 0;
    return;
  }
  float e[5];
  float s = 0.f;
  #pragma unroll
  for (int qq = 0; qq < 5; ++qq) {
    int c = qq * 64 + lane;
    float v = 0.f;
    if (c < NUM_C) v = expf(a[j * CP + c]);
    e[qq] = v;
    s += v;
  }
  #pragma unroll
  for (int o = 32; o > 0; o >>= 1) s += __shfl_xor(s, o, 64);
  float inv = 1.0f / s;
  #pragma unroll
  for (int qq = 0; qq < 5; ++qq) {
    int c = qq * 64 + lane;
    if (c < CW) wg[j * CW + c] = (c < NUM_C) ? f2bf(e[qq] * inv) : (unsigned short)0;
  }
}

// Kernel 3: out[b,j,t] = sum_c w[j,c] * X[b,c,t]  (bf16 MFMA, fp32 accum)
// k_out4: A-fragments (W) hoisted into registers for the whole block (27 x bf16x8 = 108 VGPR,
// invariant across t). LDS holds only the double-buffered X^T tile. Grid (2 jh, 128 b),
// 768 thr / 12 waves = 4 t-slices x 3 j-groups, __launch_bounds__(768,3) caps VGPR at 170.
__global__ __launch_bounds__(768, 3) void k_out4(const float* __restrict__ X,
                                                 const unsigned short* __restrict__ wg,
                                                 float* __restrict__ out) {
  extern __shared__ char lds[];
  char* XA  = lds;
  char* XBf = lds + XB_BYTES;

  const int tid = threadIdx.x;
  const int wv = tid >> 6, lane = tid & 63;
  const int rlo = lane & 15, kg = lane >> 4;
  const int jh = blockIdx.x;       // 0..1
  const int b  = blockIdx.y;       // 0..127
  const float* Xb = X + (size_t)b * (NUM_C * NUM_T);

  // staging geometry: 576 threads, thread = (c-octet co < 36, t-quad t4)
  const int co = tid >> 4;         // 0..47, stage iff < 36
  const int t4 = tid & 15;
  const bool stg = (co < 36);
  const int swz = (t4 & 3) << 4;   // row-dependent 16B XOR (t>>2 == t4 for our rows)

  // wave roles
  const int tt = wv & 3, jq = wv >> 2;       // 4 t-slices x 3 j-groups
  const int t = tt * 16 + rlo;
  const int sw = ((t >> 2) & 3) << 4;

  // ---- issue X tile 0 loads (HBM, long latency) ----
  f32x4 va[4], vb[4];
  if (stg) {
    #pragma unroll
    for (int e = 0; e < 4; ++e) {
      int c = co * 8 + e;
      if (c < NUM_C) va[e] = *(const f32x4*)(Xb + (size_t)c * NUM_T + t4 * 4);
      else { va[e][0] = va[e][1] = va[e][2] = va[e][3] = 0.f; }
    }
    #pragma unroll
    for (int e = 0; e < 4; ++e) {
      int c = co * 8 + 4 + e;
      if (c < NUM_C) vb[e] = *(const f32x4*)(Xb + (size_t)c * NUM_T + t4 * 4);
      else { vb[e][0] = vb[e][1] = vb[e][2] = vb[e][3] = 0.f; }
    }
  }

  // ---- A fragments from global wg (L2-resident), once per block ----
  bf16x8 afr[3][9];
  #pragma unroll
  for (int jt = 0; jt < 3; ++jt) {
    int row = jh * 144 + (jq * 3 + jt) * 16 + rlo;
    const char* rp = (const char*)wg + (size_t)row * ROWB + kg * 16;
    #pragma unroll
    for (int ks = 0; ks < 9; ++ks)
      afr[jt][ks] = *(const bf16x8*)(rp + ks * 64);
  }

  // ---- write tile 0 to XA ----
  if (stg) {
    char* rb = XA;
    #pragma unroll
    for (int f = 0; f < 4; ++f) {
      int tw = t4 * 4 + f;
      ushort4 pk;
      pk.x = f2bf(va[0][f]); pk.y = f2bf(va[1][f]);
      pk.z = f2bf(va[2][f]); pk.w = f2bf(va[3][f]);
      *(ushort4*)(rb + tw * ROWB + ((co * 16) ^ swz)) = pk;
    }
    #pragma unroll
    for (int f = 0; f < 4; ++f) {
      int tw = t4 * 4 + f;
      ushort4 pk;
      pk.x = f2bf(vb[0][f]); pk.y = f2bf(vb[1][f]);
      pk.z = f2bf(vb[2][f]); pk.w = f2bf(vb[3][f]);
      *(ushort4*)(rb + tw * ROWB + ((co * 16 + 8) ^ swz)) = pk;
    }
  }
  __syncthreads();

  for (int it = 0; it < 16; ++it) {
    const int t0 = it * 64;
    char* xcur = (it & 1) ? XBf : XA;
    char* xnxt = (it & 1) ? XA : XBf;
    const bool pf = stg && (it < 15);

    // phase-A prefetch of next tile (hides under MFMA)
    if (pf) {
      #pragma unroll
      for (int e = 0; e < 4; ++e) {
        int c = co * 8 + e;
        if (c < NUM_C) va[e] = *(const f32x4*)(Xb + (size_t)c * NUM_T + t0 + 64 + t4 * 4);
        else { va[e][0] = va[e][1] = va[e][2] = va[e][3] = 0.f; }
      }
    }

    // ---- compute current tile: 9 bfr reads + 27 MFMA ----
    f32x4 acc[3];
    #pragma unroll
    for (int jt = 0; jt < 3; ++jt)
      acc[jt][0] = acc[jt][1] = acc[jt][2] = acc[jt][3] = 0.f;

    #pragma unroll
    for (int ks = 0; ks < 9; ++ks) {
      bf16x8 bfr = *(const bf16x8*)(xcur + t * ROWB + ((ks * 64 + kg * 16) ^ sw));
      #pragma unroll
      for (int jt = 0; jt < 3; ++jt)
        acc[jt] = __builtin_amdgcn_mfma_f32_16x16x32_bf16(afr[jt][ks], bfr, acc[jt], 0, 0, 0);
    }

    // phase-B prefetch
    if (pf) {
      #pragma unroll
      for (int e = 0; e < 4; ++e) {
        int c = co * 8 + 4 + e;
        if (c < NUM_C) vb[e] = *(const f32x4*)(Xb + (size_t)c * NUM_T + t0 + 64 + t4 * 4);
        else { vb[e][0] = vb[e][1] = vb[e][2] = vb[e][3] = 0.f; }
      }
    }

    // stores (plain; L2 write-combines the 64B half-lines)
    #pragma unroll
    for (int jt = 0; jt < 3; ++jt) {
      #pragma unroll
      for (int r = 0; r < 4; ++r) {
        int j = jh * 144 + (jq * 3 + jt) * 16 + kg * 4 + r;
        if (j < NUM_D1)
          out[((size_t)b * NUM_D1 + j) * NUM_T + t0 + t] = acc[jt][r];
      }
    }

    if (it < 15) {
      if (pf) {
        #pragma unroll
        for (int f = 0; f < 4; ++f) {
          int tw = t4 * 4 + f;
          ushort4 pk;
          pk.x = f2bf(va[0][f]); pk.y = f2bf(va[1][f]);
          pk.z = f2bf(va[2][f]); pk.w = f2bf(va[3][f]);
          *(ushort4*)(xnxt + tw * ROWB + ((co * 16) ^ swz)) = pk;
        }
        #pragma unroll
        for (int f = 0; f < 4; ++f) {
          int tw = t4 * 4 + f;
          ushort4 pk;
          pk.x = f2bf(vb[0][f]); pk.y = f2bf(vb[1][f]);
          pk.z = f2bf(vb[2][f]); pk.w = f2bf(vb[3][f]);
          *(ushort4*)(xnxt + tw * ROWB + ((co * 16 + 8) ^ swz)) = pk;
        }
      }
      __syncthreads();
    }
  }
}

extern "C" void kernel_launch(void* const* d_in, const int* in_sizes, int n_in,
                              void* d_out, int out_size, void* d_ws, size_t ws_size,
                              hipStream_t stream) {
  const float* X   = (const float*)d_in[0];
  const float* loc = (const float*)d_in[1];
  const float* zre = (const float*)d_in[2];
  const float* zim = (const float*)d_in[3];
  float* out = (float*)d_out;
  char* ws = (char*)d_ws;
  float* cosT = (float*)(ws);
  float* sinT = (float*)(ws + 1310720);
  float* a    = (float*)(ws + 2621440);
  unsigned short* wgp = (unsigned short*)(ws + 2934784);   // [288][296] bf16 = 170,496 B

  (void)hipFuncSetAttribute((const void*)k_out4,
                            hipFuncAttributeMaxDynamicSharedMemorySize, LDS4_TOTAL);

  hipLaunchKernelGGL(k_trig,    dim3(1280),   dim3(256),  0, stream, loc, cosT, sinT);
  hipLaunchKernelGGL(k_agemm,   dim3(68, 5),  dim3(1024), 0, stream, zre, zim, cosT, sinT, a);
  hipLaunchKernelGGL(k_softmax, dim3(72),     dim3(256),  0, stream, a, wgp);
  hipLaunchKernelGGL(k_out4,    dim3(2, 128), dim3(768),  LDS4_TOTAL, stream, X, wgp, out);
}

// Round 7
// 133.280 us; speedup vs baseline: 1.7081x; 1.7081x over previous
//
#include <hip/hip_runtime.h>
#include <hip/hip_bf16.h>

#define NUM_D1 270
#define NUM_B  128
#define NUM_C  273
#define NUM_T  1024
#define KL     1024      // K*K = 32*32
#define TW     320       // trig table padded width
#define CP     288       // padded C for a[] (9 * 32)
#define CW     296       // wg / X-LDS row stride in elems (592 B = 148 dw == 20 mod 32)
#define ROWB   (CW * 2)  // 592 bytes

#define WT_BYTES (144 * ROWB)                 // 85,248
#define XB_BYTES (64 * ROWB)                  // 37,888
#define LDS5_TOTAL (WT_BYTES + 2 * XB_BYTES)  // 161,024 <= 163,840

typedef float f32x4 __attribute__((ext_vector_type(4)));
typedef __bf16 bf16x8 __attribute__((ext_vector_type(8)));

static __device__ __forceinline__ unsigned short f2bf(float f) {
  unsigned u = __float_as_uint(f);
  unsigned r = (u + 0x7fffu + ((u >> 16) & 1u)) >> 16;   // RNE
  return (unsigned short)r;
}

// Kernel 0: trig tables cos/sin(2*pi*(k*x + l*y)) for all (kl, c)
__global__ __launch_bounds__(256) void k_trig(const float* __restrict__ loc,
                                              float* __restrict__ cosT,
                                              float* __restrict__ sinT) {
  int idx = blockIdx.x * 256 + threadIdx.x;   // 0 .. 1024*320-1
  int kl = idx / TW;
  int c  = idx - kl * TW;
  float cv = 0.f, sv = 0.f;
  if (c < NUM_C) {
    float x = loc[2 * c], y = loc[2 * c + 1];
    float kf = (float)(kl >> 5), lf = (float)(kl & 31);
    float ph = 6.283185307179586f * (kf * x + lf * y);
    sincosf(ph, &sv, &cv);
  }
  cosT[idx] = cv;
  sinT[idx] = sv;
}

// Kernel 1: a[j,c] = sum_kl z_re[j,kl]*cos[kl,c] + z_im[j,kl]*sin[kl,c]
__global__ __launch_bounds__(1024) void k_agemm(const float* __restrict__ z_re,
                                                const float* __restrict__ z_im,
                                                const float* __restrict__ cosT,
                                                const float* __restrict__ sinT,
                                                float* __restrict__ a) {
  __shared__ float sm[4][8][64];
  int tid = threadIdx.x;
  int lane = tid & 63;
  int g = tid >> 6;            // 0..15
  int p = g >> 3;              // 0..1
  int q = g & 7;               // 0..7
  int jb = blockIdx.x;         // 0..67
  int cb = blockIdx.y;         // 0..4
  int c = cb * 64 + lane;      // < 320, in-bounds of padded table
  int j_a = jb * 4 + p;        // <= 269
  int j_b = j_a + 2;           // <= 271
  int jeb = (j_b < NUM_D1) ? j_b : 0;
  const float* zr0 = z_re + (size_t)j_a * KL;
  const float* zi0 = z_im + (size_t)j_a * KL;
  const float* zr1 = z_re + (size_t)jeb * KL;
  const float* zi1 = z_im + (size_t)jeb * KL;
  float a0 = 0.f, a1 = 0.f;
  int k0 = q * 128;
  #pragma unroll 4
  for (int kk = k0; kk < k0 + 128; ++kk) {
    float cv = cosT[kk * TW + c];
    float sv = sinT[kk * TW + c];
    a0 = fmaf(zr0[kk], cv, a0);
    a0 = fmaf(zi0[kk], sv, a0);
    a1 = fmaf(zr1[kk], cv, a1);
    a1 = fmaf(zi1[kk], sv, a1);
  }
  sm[p][q][lane] = a0;
  sm[p + 2][q][lane] = a1;
  __syncthreads();
  if (tid < 256) {
    int jl = tid >> 6;          // 0..3
    int l2 = tid & 63;
    int j = jb * 4 + jl;
    int c2 = cb * 64 + l2;
    float s = 0.f;
    #pragma unroll
    for (int qq = 0; qq < 8; ++qq) s += sm[jl][qq][l2];
    if (j < NUM_D1 && c2 < NUM_C) a[j * CP + c2] = s;
  }
}

// Kernel 2: w[j,:] = softmax_c(a[j,:]) -> bf16 into wg[288 rows][CW=296 stride], zero-padded
__global__ __launch_bounds__(256) void k_softmax(const float* __restrict__ a,
                                                 unsigned short* __restrict__ wg) {
  int wv = threadIdx.x >> 6;
  int lane = threadIdx.x & 63;
  int j = blockIdx.x * 4 + wv;   // < 288 (grid 72)
  if (j >= NUM_D1) {
    for (int c = lane; c < CW; c += 64) wg[j * CW + c] = 0;
    return;
  }
  float e[5];
  float s = 0.f;
  #pragma unroll
  for (int qq = 0; qq < 5; ++qq) {
    int c = qq * 64 + lane;
    float v = 0.f;
    if (c < NUM_C) v = expf(a[j * CP + c]);
    e[qq] = v;
    s += v;
  }
  #pragma unroll
  for (int o = 32; o > 0; o >>= 1) s += __shfl_xor(s, o, 64);
  float inv = 1.0f / s;
  #pragma unroll
  for (int qq = 0; qq < 5; ++qq) {
    int c = qq * 64 + lane;
    if (c < CW) wg[j * CW + c] = (c < NUM_C) ? f2bf(e[qq] * inv) : (unsigned short)0;
  }
}

// Kernel 3: out[b,j,t] = sum_c w[j,c] * X[b,c,t]  (bf16 MFMA, fp32 accum)
// k_out5: persistent, grid 256 blocks (XCD-swizzled so jh pairs share an XCD's L2),
// 768 thr / 12 waves. W-half in LDS once; X^T 64-t tiles double-buffered.
// Hot loop uses raw s_barrier + counted vmcnt: output stores stay in flight
// across the barrier; only the 8 prefetch loads must land before ds_write.
__global__ __launch_bounds__(768, 3) void k_out5(const float* __restrict__ X,
                                                 const unsigned short* __restrict__ wg,
                                                 float* __restrict__ out) {
  extern __shared__ char lds[];
  char* WTb = lds;
  char* XA  = lds + WT_BYTES;
  char* XBf = lds + WT_BYTES + XB_BYTES;

  const int tid = threadIdx.x;
  const int wv = tid >> 6, lane = tid & 63;
  const int rlo = lane & 15, kg = lane >> 4;

  // XCD-aware mapping: pair (jh=0,1) of each b lands on the same XCD
  const int lin = blockIdx.x;          // 0..255
  const int xcd = lin & 7, slot = lin >> 3;
  const int jh = slot & 1;
  const int b  = xcd * 16 + (slot >> 1);

  const float* Xb = X + (size_t)b * (NUM_C * NUM_T);

  // staging geometry: 576 threads, thread = (c-octet co < 36, t-quad t4)
  const int co = tid >> 4;         // 0..47, stage iff < 36
  const int t4 = tid & 15;
  const bool stg = (co < 36);
  const int swz = (t4 & 3) << 4;   // row-dependent 16B XOR (t>>2 == t4 for staged rows)

  // wave roles
  const int tt = wv & 3, jq = wv >> 2;       // 4 t-slices x 3 j-groups
  const int t = tt * 16 + rlo;
  const int sw = ((t >> 2) & 3) << 4;

  // ---- prologue ----
  f32x4 va[8];
  if (stg) {
    #pragma unroll
    for (int e = 0; e < 8; ++e) {
      int c = co * 8 + e;
      if (c < NUM_C) va[e] = *(const f32x4*)(Xb + (size_t)c * NUM_T + t4 * 4);
      else { va[e][0] = va[e][1] = va[e][2] = va[e][3] = 0.f; }
    }
  }
  {
    const char* wsrc = (const char*)wg + (size_t)jh * WT_BYTES;
    #pragma unroll
    for (int i = 0; i < 7; ++i) {
      int off = (tid + i * 768) * 16;
      if (off < WT_BYTES) *(uint4*)(WTb + off) = *(const uint4*)(wsrc + off);
    }
  }
  if (stg) {
    #pragma unroll
    for (int f = 0; f < 4; ++f) {
      int tw = t4 * 4 + f;
      ushort4 p0, p1;
      p0.x = f2bf(va[0][f]); p0.y = f2bf(va[1][f]);
      p0.z = f2bf(va[2][f]); p0.w = f2bf(va[3][f]);
      p1.x = f2bf(va[4][f]); p1.y = f2bf(va[5][f]);
      p1.z = f2bf(va[6][f]); p1.w = f2bf(va[7][f]);
      *(ushort4*)(XA + tw * ROWB + ((co * 16) ^ swz)) = p0;
      *(ushort4*)(XA + tw * ROWB + ((co * 16 + 8) ^ swz)) = p1;
    }
  }
  __syncthreads();   // prologue full drain is fine

  for (int it = 0; it < 16; ++it) {
    const int t0 = it * 64;
    char* xcur = (it & 1) ? XBf : XA;
    char* xnxt = (it & 1) ? XA : XBf;
    const bool pf = stg && (it < 15);

    // 1) issue next tile's 8 global loads first; fence so they aren't sunk
    if (pf) {
      #pragma unroll
      for (int e = 0; e < 8; ++e) {
        int c = co * 8 + e;
        if (c < NUM_C) va[e] = *(const f32x4*)(Xb + (size_t)c * NUM_T + t0 + 64 + t4 * 4);
        else { va[e][0] = va[e][1] = va[e][2] = va[e][3] = 0.f; }
      }
    }
    __builtin_amdgcn_sched_barrier(0);

    // 2) compute current tile: 9 bfr + 27 afr LDS reads, 27 MFMA
    f32x4 acc[3];
    #pragma unroll
    for (int jt = 0; jt < 3; ++jt)
      acc[jt][0] = acc[jt][1] = acc[jt][2] = acc[jt][3] = 0.f;

    #pragma unroll
    for (int ks = 0; ks < 9; ++ks) {
      bf16x8 bfr = *(const bf16x8*)(xcur + t * ROWB + ((ks * 64 + kg * 16) ^ sw));
      #pragma unroll
      for (int jt = 0; jt < 3; ++jt) {
        bf16x8 afr = *(const bf16x8*)(WTb +
            (size_t)((jq * 3 + jt) * 16 + rlo) * ROWB + kg * 16 + ks * 64);
        acc[jt] = __builtin_amdgcn_mfma_f32_16x16x32_bf16(afr, bfr, acc[jt], 0, 0, 0);
      }
    }

    // 3) output stores (12 per thread) — left in flight across the barrier
    #pragma unroll
    for (int jt = 0; jt < 3; ++jt) {
      #pragma unroll
      for (int r = 0; r < 4; ++r) {
        int j = jh * 144 + (jq * 3 + jt) * 16 + kg * 4 + r;
        if (j < NUM_D1)
          out[((size_t)b * NUM_D1 + j) * NUM_T + t0 + t] = acc[jt][r];
      }
    }

    if (it < 15) {
      // 4) wait only for the 8 prefetch loads (12 newer stores may linger)
      asm volatile("s_waitcnt vmcnt(12)" ::: "memory");
      __builtin_amdgcn_sched_barrier(0);
      if (pf) {
        #pragma unroll
        for (int f = 0; f < 4; ++f) {
          int tw = t4 * 4 + f;
          ushort4 p0, p1;
          p0.x = f2bf(va[0][f]); p0.y = f2bf(va[1][f]);
          p0.z = f2bf(va[2][f]); p0.w = f2bf(va[3][f]);
          p1.x = f2bf(va[4][f]); p1.y = f2bf(va[5][f]);
          p1.z = f2bf(va[6][f]); p1.w = f2bf(va[7][f]);
          *(ushort4*)(xnxt + tw * ROWB + ((co * 16) ^ swz)) = p0;
          *(ushort4*)(xnxt + tw * ROWB + ((co * 16 + 8) ^ swz)) = p1;
        }
      }
      // 5) LDS-visibility barrier WITHOUT vmcnt(0) drain
      asm volatile("s_waitcnt lgkmcnt(0)" ::: "memory");
      __builtin_amdgcn_sched_barrier(0);
      __builtin_amdgcn_s_barrier();
      __builtin_amdgcn_sched_barrier(0);
    }
  }
}

extern "C" void kernel_launch(void* const* d_in, const int* in_sizes, int n_in,
                              void* d_out, int out_size, void* d_ws, size_t ws_size,
                              hipStream_t stream) {
  const float* X   = (const float*)d_in[0];
  const float* loc = (const float*)d_in[1];
  const float* zre = (const float*)d_in[2];
  const float* zim = (const float*)d_in[3];
  float* out = (float*)d_out;
  char* ws = (char*)d_ws;
  float* cosT = (float*)(ws);
  float* sinT = (float*)(ws + 1310720);
  float* a    = (float*)(ws + 2621440);
  unsigned short* wgp = (unsigned short*)(ws + 2934784);   // [288][296] bf16 = 170,496 B

  (void)hipFuncSetAttribute((const void*)k_out5,
                            hipFuncAttributeMaxDynamicSharedMemorySize, LDS5_TOTAL);

  hipLaunchKernelGGL(k_trig,    dim3(1280),   dim3(256),  0, stream, loc, cosT, sinT);
  hipLaunchKernelGGL(k_agemm,   dim3(68, 5),  dim3(1024), 0, stream, zre, zim, cosT, sinT, a);
  hipLaunchKernelGGL(k_softmax, dim3(72),     dim3(256),  0, stream, a, wgp);
  hipLaunchKernelGGL(k_out5,    dim3(256),    dim3(768),  LDS5_TOTAL, stream, X, wgp, out);
}